// Round 3
// baseline (12275.518 us; speedup 1.0000x reference)
//
#include <hip/hip_runtime.h>
#include <hip/hip_cooperative_groups.h>

namespace cg = cooperative_groups;

#define DEV static __device__ __forceinline__

DEV float sigf(float x) { return 1.0f / (1.0f + __expf(-x)); }
DEV float ftanh(float x) {
  float xc = fminf(fmaxf(x, -9.0f), 9.0f);
  float e = __expf(2.0f * xc);
  return (e - 1.0f) / (e + 1.0f);
}

// ---------------- generic tiled f32 GEMM (NT): out[m][n] = sum_k A[m][k]*B[n][k] + bias[n]
__global__ __launch_bounds__(256) void gemm_nt_bias(
    const float* __restrict__ A, const float* __restrict__ B,
    const float* __restrict__ bias, float* __restrict__ out,
    int M, int N, int K)
{
  __shared__ float As[64][17];
  __shared__ float Bs[64][17];
  const int tid = threadIdx.x;
  const int m0 = blockIdx.y * 64, n0 = blockIdx.x * 64;
  const int lr = tid >> 2;          // 0..63
  const int lk = (tid & 3) << 2;    // 0,4,8,12
  const int ty = tid >> 4, tx = tid & 15;
  float acc[4][4] = {};
  for (int k0 = 0; k0 < K; k0 += 16) {
    float4 a4 = *(const float4*)(A + (size_t)(m0 + lr) * K + k0 + lk);
    float4 b4 = *(const float4*)(B + (size_t)(n0 + lr) * K + k0 + lk);
    As[lr][lk] = a4.x; As[lr][lk + 1] = a4.y; As[lr][lk + 2] = a4.z; As[lr][lk + 3] = a4.w;
    Bs[lr][lk] = b4.x; Bs[lr][lk + 1] = b4.y; Bs[lr][lk + 2] = b4.z; Bs[lr][lk + 3] = b4.w;
    __syncthreads();
#pragma unroll
    for (int kk = 0; kk < 16; ++kk) {
      float av[4], bv[4];
#pragma unroll
      for (int r = 0; r < 4; ++r) av[r] = As[ty * 4 + r][kk];
#pragma unroll
      for (int c = 0; c < 4; ++c) bv[c] = Bs[tx * 4 + c][kk];
#pragma unroll
      for (int r = 0; r < 4; ++r)
#pragma unroll
        for (int c = 0; c < 4; ++c) acc[r][c] = fmaf(av[r], bv[c], acc[r][c]);
    }
    __syncthreads();
  }
#pragma unroll
  for (int r = 0; r < 4; ++r) {
    int m = m0 + ty * 4 + r;
#pragma unroll
    for (int c = 0; c < 4; ++c) {
      int n = n0 + tx * 4 + c;
      out[(size_t)m * N + n] = acc[r][c] + bias[n];
    }
  }
}

struct Params {
  const float* x;        // [32][32][2048]  (y_emb@W.T + b, precomputed)
  const float* pctx;     // [128][32][1024]
  const float* context;  // [128][32][1024]
  const float* init_h;   // [32][512]
  const float* init_c;   // [32][512]
  const float* x_mask;   // [128][32]
  const float* y_mask;   // [32][32]
  const float* U;        // [2048][512]
  const float* Wcomb;    // [1024][512]
  const float* U_att;    // [1024]
  const float* Ux;       // [2048][512]
  const float* Wx;       // [2048][1024]
  const float* bx;       // [2048]
  float* hs;             // out [32][32][512]
  float* cs;             // out [32][32][512]
  float* atts;           // out [32][32][1024]
  float* hT;             // ws [128 k4][32 b] float4
  float* h1;             // ws [32][512]
  float* h1T;            // ws [128][32] float4
  float* c1;             // ws [32][512]
  float* hproj;          // ws [32][1024]
  float* score;          // ws [128][32]
  float* attT;           // ws [256 c4][32 b] float4
};

// Persistent cooperative kernel: all 32 decode steps, 5 grid syncs per step.
// Grid MUST be 512 blocks x 256 threads (2 blocks/CU on 256 CUs).
__global__ __launch_bounds__(256, 2) void decoder_persistent(Params p)
{
  cg::grid_group grid = cg::this_grid();
  const int bid = blockIdx.x;   // 0..511
  const int tid = threadIdx.x;  // 0..255
  __shared__ float lds[512];

  // ---- phase 0: hT = transpose(init_h) as float4 [128][32]
  {
    int idx = bid * 256 + tid;
    if (idx < 4096) {
      int k4 = idx >> 5, b = idx & 31;
      ((float4*)p.hT)[idx] = ((const float4*)p.init_h)[b * 128 + k4];
    }
  }
  grid.sync();

  for (int t = 0; t < 32; ++t) {
    const float* cp = t ? p.cs + (size_t)(t - 1) * 16384 : p.init_c;
    const float* xt = p.x + (size_t)t * 65536;
    const float* ym = p.y_mask + t * 32;

    // ---- P1: lstm1. One j per block; slots = gate(2b)|khalf(1b), b = tid&31.
    {
      const int b = tid & 31;
      const int slot = tid >> 5;       // 0..7
      const int kh = slot & 1;
      const int gate = slot >> 1;      // 0:i 1:f 2:o 3:g
      const int j = bid;
      const float* urow = p.U + ((size_t)(gate * 512 + j)) * 512 + kh * 256;
      const float4* hT4 = (const float4*)p.hT + kh * 64 * 32;
      float acc = 0.f;
#pragma unroll 8
      for (int k4 = 0; k4 < 64; ++k4) {
        float4 h4 = hT4[k4 * 32 + b];
        float4 u4 = *(const float4*)(urow + k4 * 4);
        acc = fmaf(h4.x, u4.x, fmaf(h4.y, u4.y, fmaf(h4.z, u4.z, fmaf(h4.w, u4.w, acc))));
      }
      lds[slot * 32 + b] = acc;
      __syncthreads();
      if (tid < 32) {
        const int b2 = tid;
        float pi = xt[b2 * 2048 + j]        + lds[b2]        + lds[32 + b2];
        float pf = xt[b2 * 2048 + 512 + j]  + lds[64 + b2]   + lds[96 + b2];
        float po = xt[b2 * 2048 + 1024 + j] + lds[128 + b2]  + lds[160 + b2];
        float pg = xt[b2 * 2048 + 1536 + j] + lds[192 + b2]  + lds[224 + b2];
        float cold = cp[b2 * 512 + j];
        float cn = sigf(pf) * cold + sigf(pi) * tanhf(pg);
        float hn = sigf(po) * tanhf(cn);
        float ymv = ym[b2];
        float hfall = p.hT[(j >> 2) * 128 + b2 * 4 + (j & 3)];
        float hm = ymv * hn + (1.f - ymv) * hfall;
        p.h1[b2 * 512 + j] = hm;
        p.h1T[(j >> 2) * 128 + b2 * 4 + (j & 3)] = hm;
        p.c1[b2 * 512 + j] = cn;   // unmasked, matches reference
      }
    }
    grid.sync();

    // ---- P2: hproj[b][d] = h1 . Wcomb[d], 2 d per block, split-K x4.
    {
      const int b = tid & 31;
      const int dl = (tid >> 5) & 1;
      const int kq = tid >> 6;   // 0..3
      const int d = bid * 2 + dl;
      const float* wrow = p.Wcomb + (size_t)d * 512 + kq * 128;
      const float4* h4p = (const float4*)p.h1T + kq * 32 * 32;
      float acc = 0.f;
#pragma unroll 8
      for (int k4 = 0; k4 < 32; ++k4) {
        float4 h4 = h4p[k4 * 32 + b];
        float4 w4 = *(const float4*)(wrow + k4 * 4);
        acc = fmaf(h4.x, w4.x, fmaf(h4.y, w4.y, fmaf(h4.z, w4.z, fmaf(h4.w, w4.w, acc))));
      }
      lds[tid] = acc;            // tid = kq*64 + dl*32 + b
      __syncthreads();
      if (tid < 64) {
        const int bb = tid & 31, dll = tid >> 5;
        float s = lds[dll * 32 + bb] + lds[64 + dll * 32 + bb]
                + lds[128 + dll * 32 + bb] + lds[192 + dll * 32 + bb];
        p.hproj[bb * 1024 + bid * 2 + dll] = s;
      }
    }
    grid.sync();

    // ---- P3: score[tx][b] = xm * sum_c tanh(pctx+hproj)*U_att. 8 (tx,b) per block.
    {
      const int s = tid >> 5, lane = tid & 31;
      const int pr = bid * 8 + s;          // 0..4095
      const int tx = pr >> 5, b = pr & 31;
      const float4* pc = (const float4*)(p.pctx + ((size_t)tx * 32 + b) * 1024);
      const float4* hp = (const float4*)(p.hproj + (size_t)b * 1024);
      const float4* ua = (const float4*)p.U_att;
      float acc = 0.f;
#pragma unroll
      for (int i = 0; i < 8; ++i) {
        int c4 = i * 32 + lane;
        float4 pv = pc[c4], hv = hp[c4], uv = ua[c4];
        acc += ftanh(pv.x + hv.x) * uv.x + ftanh(pv.y + hv.y) * uv.y
             + ftanh(pv.z + hv.z) * uv.z + ftanh(pv.w + hv.w) * uv.w;
      }
#pragma unroll
      for (int off = 16; off > 0; off >>= 1) acc += __shfl_down(acc, off, 32);
      if (lane == 0) p.score[tx * 32 + b] = acc * p.x_mask[tx * 32 + b];
    }
    grid.sync();

    // ---- P4: per-block softmax + atted. block: b = bid>>4, c-chunk = bid&15 (64 c).
    {
      const int b = bid >> 4, cch = bid & 15;
      if (tid < 128) lds[tid] = p.score[tid * 32 + b];
      __syncthreads();
      if (tid < 64) {
        float m = fmaxf(lds[tid], lds[tid + 64]);
#pragma unroll
        for (int off = 32; off > 0; off >>= 1) m = fmaxf(m, __shfl_down(m, off));
        if (tid == 0) lds[200] = m;
      }
      __syncthreads();
      const float mx = lds[200];
      if (tid < 128) lds[tid] = __expf(lds[tid] - mx) * p.x_mask[tid * 32 + b];
      __syncthreads();
      if (tid < 64) {
        float sm = lds[tid] + lds[tid + 64];
#pragma unroll
        for (int off = 32; off > 0; off >>= 1) sm += __shfl_down(sm, off);
        if (tid == 0) lds[201] = sm;
      }
      __syncthreads();
      const float inv = 1.0f / lds[201];
      const int cl = tid & 63, tq = tid >> 6;
      const int c = cch * 64 + cl;
      float acc = 0.f;
      const float* ctx = p.context;
#pragma unroll 8
      for (int i = 0; i < 32; ++i) {
        int tt = tq * 32 + i;
        acc = fmaf(lds[tt], ctx[((size_t)tt * 32 + b) * 1024 + c], acc);
      }
      lds[256 + tid] = acc;     // tid = tq*64 + cl
      __syncthreads();
      if (tid < 64) {
        float tot = (lds[256 + tid] + lds[256 + 64 + tid]
                   + lds[256 + 128 + tid] + lds[256 + 192 + tid]) * inv;
        const int cc = cch * 64 + tid;
        p.atts[(size_t)t * 32768 + b * 1024 + cc] = tot;
        p.attT[(cc >> 2) * 128 + b * 4 + (cc & 3)] = tot;
      }
    }
    grid.sync();

    // ---- P5: lstm2. One j per block; pre2 = h1.Ux + atted.Wx + bx.
    {
      const int b = tid & 31;
      const int slot = tid >> 5;
      const int kh = slot & 1;
      const int gate = slot >> 1;
      const int j = bid;
      const float* uxrow = p.Ux + ((size_t)(gate * 512 + j)) * 512 + kh * 256;
      const float* wxrow = p.Wx + ((size_t)(gate * 512 + j)) * 1024 + kh * 512;
      const float4* h4p = (const float4*)p.h1T + kh * 64 * 32;
      const float4* a4p = (const float4*)p.attT + kh * 128 * 32;
      float acc = 0.f;
#pragma unroll 8
      for (int k4 = 0; k4 < 64; ++k4) {
        float4 h4 = h4p[k4 * 32 + b];
        float4 u4 = *(const float4*)(uxrow + k4 * 4);
        acc = fmaf(h4.x, u4.x, fmaf(h4.y, u4.y, fmaf(h4.z, u4.z, fmaf(h4.w, u4.w, acc))));
      }
#pragma unroll 8
      for (int c4 = 0; c4 < 128; ++c4) {
        float4 v4 = a4p[c4 * 32 + b];
        float4 w4 = *(const float4*)(wxrow + c4 * 4);
        acc = fmaf(v4.x, w4.x, fmaf(v4.y, w4.y, fmaf(v4.z, w4.z, fmaf(v4.w, w4.w, acc))));
      }
      lds[slot * 32 + b] = acc;
      __syncthreads();
      if (tid < 32) {
        const int b2 = tid;
        float pi = p.bx[j]        + lds[b2]       + lds[32 + b2];
        float pf = p.bx[512 + j]  + lds[64 + b2]  + lds[96 + b2];
        float po = p.bx[1024 + j] + lds[128 + b2] + lds[160 + b2];
        float pg = p.bx[1536 + j] + lds[192 + b2] + lds[224 + b2];
        float c1v = p.c1[b2 * 512 + j];
        float cn = sigf(pf) * c1v + sigf(pi) * tanhf(pg);
        float hn = sigf(po) * tanhf(cn);
        float ymv = ym[b2];
        float hf = p.h1[b2 * 512 + j];
        float hm = ymv * hn + (1.f - ymv) * hf;
        p.hs[(size_t)t * 16384 + b2 * 512 + j] = hm;
        p.cs[(size_t)t * 16384 + b2 * 512 + j] = cn;
        p.hT[(j >> 2) * 128 + b2 * 4 + (j & 3)] = hm;
      }
    }
    grid.sync();
  }
}

extern "C" void kernel_launch(void* const* d_in, const int* in_sizes, int n_in,
                              void* d_out, int out_size, void* d_ws, size_t ws_size,
                              hipStream_t stream)
{
  const float* y_emb   = (const float*)d_in[0];
  const float* context = (const float*)d_in[1];
  const float* init_h  = (const float*)d_in[2];
  const float* init_c  = (const float*)d_in[3];
  const float* x_mask  = (const float*)d_in[4];
  const float* y_mask  = (const float*)d_in[5];
  const float* W       = (const float*)d_in[6];
  const float* U       = (const float*)d_in[7];
  const float* bvec    = (const float*)d_in[8];
  const float* Wx      = (const float*)d_in[9];
  const float* Ux      = (const float*)d_in[10];
  const float* bx      = (const float*)d_in[11];
  const float* Wc      = (const float*)d_in[12];
  const float* b_att   = (const float*)d_in[13];
  const float* Wcomb   = (const float*)d_in[14];
  const float* U_att   = (const float*)d_in[15];

  float* out  = (float*)d_out;
  float* hs   = out;                              // [32][32][512]
  float* cs   = out + (size_t)32 * 32 * 512;      // [32][32][512]
  float* atts = out + (size_t)2 * 32 * 32 * 512;  // [32][32][1024]

  float* ws    = (float*)d_ws;
  float* pctx  = ws;                 // 4194304 floats
  float* x     = pctx + 4194304;     // 2097152 floats
  float* h1    = x + 2097152;        // 16384
  float* c1    = h1 + 16384;         // 16384
  float* hproj = c1 + 16384;         // 32768
  float* score = hproj + 32768;      // 4096
  float* hT    = score + 4096;       // 16384
  float* h1T   = hT + 16384;         // 16384
  float* attT  = h1T + 16384;        // 32768

  gemm_nt_bias<<<dim3(1024 / 64, 4096 / 64), 256, 0, stream>>>(context, Wc, b_att, pctx, 4096, 1024, 1024);
  gemm_nt_bias<<<dim3(2048 / 64, 1024 / 64), 256, 0, stream>>>(y_emb, W, bvec, x, 1024, 2048, 256);

  Params prm;
  prm.x = x; prm.pctx = pctx; prm.context = context;
  prm.init_h = init_h; prm.init_c = init_c;
  prm.x_mask = x_mask; prm.y_mask = y_mask;
  prm.U = U; prm.Wcomb = Wcomb; prm.U_att = U_att;
  prm.Ux = Ux; prm.Wx = Wx; prm.bx = bx;
  prm.hs = hs; prm.cs = cs; prm.atts = atts;
  prm.hT = hT; prm.h1 = h1; prm.h1T = h1T; prm.c1 = c1;
  prm.hproj = hproj; prm.score = score; prm.attT = attT;

  void* kargs[] = { &prm };
  hipLaunchCooperativeKernel((const void*)decoder_persistent,
                             dim3(512), dim3(256), kargs, 0, stream);
}

// Round 4
// 2039.181 us; speedup vs baseline: 6.0198x; 6.0198x over previous
//
#include <hip/hip_runtime.h>

#define DEV static __device__ __forceinline__

DEV float sigf(float x) { return 1.0f / (1.0f + __expf(-x)); }
DEV float ftanh(float x) {
  float xc = fminf(fmaxf(x, -9.0f), 9.0f);
  float e = __expf(2.0f * xc);
  return (e - 1.0f) / (e + 1.0f);
}

// ---------------- generic tiled f32 GEMM (NT): out[m][n] = sum_k A[m][k]*B[n][k] + bias[n]
__global__ __launch_bounds__(256) void gemm_nt_bias(
    const float* __restrict__ A, const float* __restrict__ B,
    const float* __restrict__ bias, float* __restrict__ out,
    int M, int N, int K)
{
  __shared__ float As[64][17];
  __shared__ float Bs[64][17];
  const int tid = threadIdx.x;
  const int m0 = blockIdx.y * 64, n0 = blockIdx.x * 64;
  const int lr = tid >> 2;
  const int lk = (tid & 3) << 2;
  const int ty = tid >> 4, tx = tid & 15;
  float acc[4][4] = {};
  for (int k0 = 0; k0 < K; k0 += 16) {
    float4 a4 = *(const float4*)(A + (size_t)(m0 + lr) * K + k0 + lk);
    float4 b4 = *(const float4*)(B + (size_t)(n0 + lr) * K + k0 + lk);
    As[lr][lk] = a4.x; As[lr][lk + 1] = a4.y; As[lr][lk + 2] = a4.z; As[lr][lk + 3] = a4.w;
    Bs[lr][lk] = b4.x; Bs[lr][lk + 1] = b4.y; Bs[lr][lk + 2] = b4.z; Bs[lr][lk + 3] = b4.w;
    __syncthreads();
#pragma unroll
    for (int kk = 0; kk < 16; ++kk) {
      float av[4], bv[4];
#pragma unroll
      for (int r = 0; r < 4; ++r) av[r] = As[ty * 4 + r][kk];
#pragma unroll
      for (int c = 0; c < 4; ++c) bv[c] = Bs[tx * 4 + c][kk];
#pragma unroll
      for (int r = 0; r < 4; ++r)
#pragma unroll
        for (int c = 0; c < 4; ++c) acc[r][c] = fmaf(av[r], bv[c], acc[r][c]);
    }
    __syncthreads();
  }
#pragma unroll
  for (int r = 0; r < 4; ++r) {
    int m = m0 + ty * 4 + r;
#pragma unroll
    for (int c = 0; c < 4; ++c) {
      int n = n0 + tx * 4 + c;
      out[(size_t)m * N + n] = acc[r][c] + bias[n];
    }
  }
}

__global__ void transpose_h(const float* __restrict__ src /*[32][512]*/,
                            float* __restrict__ dstT /*[128][32] float4*/)
{
  int idx = blockIdx.x * 256 + threadIdx.x;
  if (idx < 4096) {
    int k4 = idx >> 5, b = idx & 31;
    ((float4*)dstT)[idx] = ((const float4*)src)[b * 128 + k4];
  }
}

// ---------------- K1: lstm1, 512 blocks (one j each), slots = gate(2b)|khalf(1b)
__global__ __launch_bounds__(256) void lstm1_k(
    const float* __restrict__ xt, const float* __restrict__ hT,
    const float* __restrict__ cprev, const float* __restrict__ U,
    const float* __restrict__ ym,
    float* __restrict__ h1, float* __restrict__ h1T, float* __restrict__ c1)
{
  const int tid = threadIdx.x;
  const int b = tid & 31;
  const int slot = tid >> 5;     // 0..7
  const int kh = slot & 1;
  const int gate = slot >> 1;    // 0:i 1:f 2:o 3:g
  const int j = blockIdx.x;      // 0..511
  const float* urow = U + (size_t)(gate * 512 + j) * 512 + kh * 256;
  const float4* h4p = (const float4*)hT + kh * 64 * 32;
  float acc = 0.f;
#pragma unroll 8
  for (int k4 = 0; k4 < 64; ++k4) {
    float4 h4 = h4p[k4 * 32 + b];
    float4 u4 = *(const float4*)(urow + k4 * 4);
    acc = fmaf(h4.x, u4.x, fmaf(h4.y, u4.y, fmaf(h4.z, u4.z, fmaf(h4.w, u4.w, acc))));
  }
  __shared__ float lds[256];
  lds[slot * 32 + b] = acc;
  __syncthreads();
  if (tid < 32) {
    const int b2 = tid;
    float pi = xt[b2 * 2048 + j]        + lds[b2]        + lds[32 + b2];
    float pf = xt[b2 * 2048 + 512 + j]  + lds[64 + b2]   + lds[96 + b2];
    float po = xt[b2 * 2048 + 1024 + j] + lds[128 + b2]  + lds[160 + b2];
    float pg = xt[b2 * 2048 + 1536 + j] + lds[192 + b2]  + lds[224 + b2];
    float cold = cprev[b2 * 512 + j];
    float cn = sigf(pf) * cold + sigf(pi) * tanhf(pg);
    float hn = sigf(po) * tanhf(cn);
    float ymv = ym[b2];
    float hfall = hT[(j >> 2) * 128 + b2 * 4 + (j & 3)];
    float hm = ymv * hn + (1.f - ymv) * hfall;
    h1[b2 * 512 + j] = hm;
    h1T[(j >> 2) * 128 + b2 * 4 + (j & 3)] = hm;
    c1[b2 * 512 + j] = cn;   // unmasked, matches reference
  }
}

// ---------------- K2: hproj, 512 blocks (2 d each), split-K x4
__global__ __launch_bounds__(256) void hproj_k(
    const float* __restrict__ h1T, const float* __restrict__ Wcomb,
    float* __restrict__ hproj)
{
  const int tid = threadIdx.x;
  const int b = tid & 31;
  const int dl = (tid >> 5) & 1;
  const int kq = tid >> 6;   // 0..3
  const int d = blockIdx.x * 2 + dl;
  const float* wrow = Wcomb + (size_t)d * 512 + kq * 128;
  const float4* h4p = (const float4*)h1T + kq * 32 * 32;
  float acc = 0.f;
#pragma unroll 8
  for (int k4 = 0; k4 < 32; ++k4) {
    float4 h4 = h4p[k4 * 32 + b];
    float4 w4 = *(const float4*)(wrow + k4 * 4);
    acc = fmaf(h4.x, w4.x, fmaf(h4.y, w4.y, fmaf(h4.z, w4.z, fmaf(h4.w, w4.w, acc))));
  }
  __shared__ float lds[256];
  lds[tid] = acc;            // tid = kq*64 + dl*32 + b
  __syncthreads();
  if (tid < 64) {
    const int bb = tid & 31, dll = tid >> 5;
    float s = lds[dll * 32 + bb] + lds[64 + dll * 32 + bb]
            + lds[128 + dll * 32 + bb] + lds[192 + dll * 32 + bb];
    hproj[bb * 1024 + blockIdx.x * 2 + dll] = s;
  }
}

// ---------------- K3: e[t][b] = exp(xm * sum_c tanh(pctx+hproj)*U_att) * xm
// (max-subtraction skipped: cancels exactly in the softmax ratio)
__global__ __launch_bounds__(256) void score_k(
    const float* __restrict__ pctx, const float* __restrict__ hproj,
    const float* __restrict__ U_att, const float* __restrict__ x_mask,
    float* __restrict__ evals /*[128][32]*/)
{
  const int t = blockIdx.x;
  const int b = blockIdx.y * 4 + (threadIdx.x >> 6);
  const int lane = threadIdx.x & 63;
  const float4* pr = (const float4*)(pctx + ((size_t)t * 32 + b) * 1024);
  const float4* hp = (const float4*)(hproj + (size_t)b * 1024);
  const float4* ua = (const float4*)U_att;
  float acc = 0.f;
#pragma unroll
  for (int i = 0; i < 4; ++i) {
    int c4 = i * 64 + lane;
    float4 p = pr[c4], h = hp[c4], u = ua[c4];
    acc += ftanh(p.x + h.x) * u.x + ftanh(p.y + h.y) * u.y
         + ftanh(p.z + h.z) * u.z + ftanh(p.w + h.w) * u.w;
  }
#pragma unroll
  for (int off = 32; off > 0; off >>= 1) acc += __shfl_down(acc, off);
  if (lane == 0) {
    float xm = x_mask[t * 32 + b];
    evals[t * 32 + b] = __expf(acc * xm) * xm;
  }
}

// ---------------- K4: normalize + atted. block: b = bid.x, c-chunk = bid.y (128 c).
__global__ __launch_bounds__(256) void atted_k(
    const float* __restrict__ evals, const float* __restrict__ context,
    float* __restrict__ atts_t /*[32][1024]*/, float* __restrict__ attedT)
{
  const int b = blockIdx.x, cc = blockIdx.y;
  const int tid = threadIdx.x;
  __shared__ float sc[128];
  __shared__ float red;
  __shared__ float4 part[8][32];
  if (tid < 128) sc[tid] = evals[tid * 32 + b];
  __syncthreads();
  if (tid < 64) {
    float s = sc[tid] + sc[tid + 64];
#pragma unroll
    for (int off = 32; off > 0; off >>= 1) s += __shfl_down(s, off);
    if (tid == 0) red = s;
  }
  __syncthreads();
  const float inv = 1.0f / red;
  const int c4 = tid & 31, tg = tid >> 5;
  const float4* ctx4 = (const float4*)context;
  float4 acc = make_float4(0.f, 0.f, 0.f, 0.f);
  for (int t = tg; t < 128; t += 8) {
    float a = sc[t];
    float4 v = ctx4[((size_t)t * 32 + b) * 256 + cc * 32 + c4];
    acc.x = fmaf(a, v.x, acc.x); acc.y = fmaf(a, v.y, acc.y);
    acc.z = fmaf(a, v.z, acc.z); acc.w = fmaf(a, v.w, acc.w);
  }
  part[tg][c4] = acc;
  __syncthreads();
  if (tid < 32) {
    float4 tot = part[0][tid];
#pragma unroll
    for (int g = 1; g < 8; ++g) {
      float4 p = part[g][tid];
      tot.x += p.x; tot.y += p.y; tot.z += p.z; tot.w += p.w;
    }
    tot.x *= inv; tot.y *= inv; tot.z *= inv; tot.w *= inv;
    ((float4*)(atts_t + (size_t)b * 1024 + cc * 128))[tid] = tot;
    const int cbase = cc * 32 + tid;   // float4 index within 256
    ((float4*)attedT)[(size_t)cbase * 32 + b] = tot;
  }
}

// ---------------- K5: lstm2, 512 blocks (one j each)
__global__ __launch_bounds__(256) void lstm2_k(
    const float* __restrict__ h1, const float* __restrict__ h1T,
    const float* __restrict__ c1, const float* __restrict__ attT,
    const float* __restrict__ Ux, const float* __restrict__ Wx,
    const float* __restrict__ bx, const float* __restrict__ ym,
    float* __restrict__ hs_t, float* __restrict__ cs_t,
    float* __restrict__ hT_next)
{
  const int tid = threadIdx.x;
  const int b = tid & 31;
  const int slot = tid >> 5;
  const int kh = slot & 1;
  const int gate = slot >> 1;
  const int j = blockIdx.x;
  const float* uxrow = Ux + (size_t)(gate * 512 + j) * 512 + kh * 256;
  const float* wxrow = Wx + (size_t)(gate * 512 + j) * 1024 + kh * 512;
  const float4* h4p = (const float4*)h1T + kh * 64 * 32;
  const float4* a4p = (const float4*)attT + kh * 128 * 32;
  float acc = 0.f;
#pragma unroll 8
  for (int k4 = 0; k4 < 64; ++k4) {
    float4 h4 = h4p[k4 * 32 + b];
    float4 u4 = *(const float4*)(uxrow + k4 * 4);
    acc = fmaf(h4.x, u4.x, fmaf(h4.y, u4.y, fmaf(h4.z, u4.z, fmaf(h4.w, u4.w, acc))));
  }
#pragma unroll 8
  for (int c4 = 0; c4 < 128; ++c4) {
    float4 v4 = a4p[c4 * 32 + b];
    float4 w4 = *(const float4*)(wxrow + c4 * 4);
    acc = fmaf(v4.x, w4.x, fmaf(v4.y, w4.y, fmaf(v4.z, w4.z, fmaf(v4.w, w4.w, acc))));
  }
  __shared__ float lds[256];
  lds[slot * 32 + b] = acc;
  __syncthreads();
  if (tid < 32) {
    const int b2 = tid;
    float pi = bx[j]        + lds[b2]       + lds[32 + b2];
    float pf = bx[512 + j]  + lds[64 + b2]  + lds[96 + b2];
    float po = bx[1024 + j] + lds[128 + b2] + lds[160 + b2];
    float pg = bx[1536 + j] + lds[192 + b2] + lds[224 + b2];
    float c1v = c1[b2 * 512 + j];
    float cn = sigf(pf) * c1v + sigf(pi) * tanhf(pg);
    float hn = sigf(po) * tanhf(cn);
    float ymv = ym[b2];
    float hf = h1[b2 * 512 + j];
    float hm = ymv * hn + (1.f - ymv) * hf;
    hs_t[b2 * 512 + j] = hm;
    cs_t[b2 * 512 + j] = cn;
    hT_next[(j >> 2) * 128 + b2 * 4 + (j & 3)] = hm;
  }
}

extern "C" void kernel_launch(void* const* d_in, const int* in_sizes, int n_in,
                              void* d_out, int out_size, void* d_ws, size_t ws_size,
                              hipStream_t stream)
{
  const float* y_emb   = (const float*)d_in[0];
  const float* context = (const float*)d_in[1];
  const float* init_h  = (const float*)d_in[2];
  const float* init_c  = (const float*)d_in[3];
  const float* x_mask  = (const float*)d_in[4];
  const float* y_mask  = (const float*)d_in[5];
  const float* W       = (const float*)d_in[6];
  const float* U       = (const float*)d_in[7];
  const float* bvec    = (const float*)d_in[8];
  const float* Wx      = (const float*)d_in[9];
  const float* Ux      = (const float*)d_in[10];
  const float* bx      = (const float*)d_in[11];
  const float* Wc      = (const float*)d_in[12];
  const float* b_att   = (const float*)d_in[13];
  const float* Wcomb   = (const float*)d_in[14];
  const float* U_att   = (const float*)d_in[15];

  float* out  = (float*)d_out;
  float* hs   = out;
  float* cs   = out + (size_t)32 * 32 * 512;
  float* atts = out + (size_t)2 * 32 * 32 * 512;

  float* ws    = (float*)d_ws;
  float* pctx  = ws;
  float* x     = pctx + 4194304;
  float* h1    = x + 2097152;
  float* c1    = h1 + 16384;
  float* hproj = c1 + 16384;
  float* evals = hproj + 32768;
  float* hT    = evals + 4096;
  float* h1T   = hT + 16384;
  float* attT  = h1T + 16384;

  gemm_nt_bias<<<dim3(16, 64), 256, 0, stream>>>(context, Wc, b_att, pctx, 4096, 1024, 1024);
  gemm_nt_bias<<<dim3(32, 16), 256, 0, stream>>>(y_emb, W, bvec, x, 1024, 2048, 256);
  transpose_h<<<16, 256, 0, stream>>>(init_h, hT);

  for (int t = 0; t < 32; ++t) {
    const float* cp = t ? cs + (size_t)(t - 1) * 16384 : init_c;
    lstm1_k<<<512, 256, 0, stream>>>(x + (size_t)t * 65536, hT, cp, U, y_mask + t * 32, h1, h1T, c1);
    hproj_k<<<512, 256, 0, stream>>>(h1T, Wcomb, hproj);
    score_k<<<dim3(128, 8), 256, 0, stream>>>(pctx, hproj, U_att, x_mask, evals);
    atted_k<<<dim3(32, 8), 256, 0, stream>>>(evals, context, atts + (size_t)t * 32768, attT);
    lstm2_k<<<512, 256, 0, stream>>>(h1, h1T, c1, attT, Ux, Wx, bx, y_mask + t * 32,
                                     hs + (size_t)t * 16384, cs + (size_t)t * 16384, hT);
  }
}